// Round 2
// baseline (118.499 us; speedup 1.0000x reference)
//
#include <hip/hip_runtime.h>

// IMMLoss: B=32 groups, M=4 rows, D=196608 features, f32.
// loss = mean_b( wtout[b] * (mean K(st,st) + mean K(sr,sr) - 2*mean K(st,sr)) )
// K(x,y)_ij = exp(clip(-w[b]*sqrt(max(|x_i-y_j|^2,1e-12))/D, -1e6, 0))
// |x_i-y_j|^2 via gram expansion: xn_i + yn_j - 2*xy_ij.

constexpr int NB = 32;       // groups
constexpr int MM = 4;        // rows per group
constexpr int DD = 196608;   // feature dim
constexpr int D4 = DD / 4;   // 49152 float4 per row
constexpr int BPG = 64;      // blocks per group -> 2048 blocks total
constexpr int NTHREADS = 256;
constexpr int CHUNK4 = D4 / BPG;          // 768 float4 per block per row
constexpr int IPT = CHUNK4 / NTHREADS;    // 3 float4 indices per thread
constexpr int NACC = 36;                  // 10 ss-tri + 10 rr-tri + 16 cross

__device__ __forceinline__ float dot4(const float4& a, const float4& b) {
    return a.x * b.x + a.y * b.y + a.z * b.z + a.w * b.w;
}

__global__ __launch_bounds__(NTHREADS) void mmd_partial_kernel(
    const float* __restrict__ st, const float* __restrict__ sr,
    float* __restrict__ partial)
{
    const int b   = blockIdx.x >> 6;   // / BPG
    const int blk = blockIdx.x & 63;   // % BPG
    const float4* __restrict__ stb =
        reinterpret_cast<const float4*>(st) + (size_t)b * MM * D4;
    const float4* __restrict__ srb =
        reinterpret_cast<const float4*>(sr) + (size_t)b * MM * D4;
    const int i0 = blk * CHUNK4 + (int)threadIdx.x;

    // Hoist ALL loads: 24 independent global_load_dwordx4 in flight per thread.
    float4 x[IPT][MM], y[IPT][MM];
#pragma unroll
    for (int u = 0; u < IPT; ++u) {
        const int idx = i0 + u * NTHREADS;
#pragma unroll
        for (int i = 0; i < MM; ++i) x[u][i] = stb[(size_t)i * D4 + idx];
#pragma unroll
        for (int i = 0; i < MM; ++i) y[u][i] = srb[(size_t)i * D4 + idx];
    }

    float acc[NACC];
#pragma unroll
    for (int k = 0; k < NACC; ++k) acc[k] = 0.0f;

#pragma unroll
    for (int u = 0; u < IPT; ++u) {
        int k = 0;
#pragma unroll
        for (int i = 0; i < MM; ++i)
#pragma unroll
            for (int j = i; j < MM; ++j) { acc[k] += dot4(x[u][i], x[u][j]); ++k; }
#pragma unroll
        for (int i = 0; i < MM; ++i)
#pragma unroll
            for (int j = i; j < MM; ++j) { acc[k] += dot4(y[u][i], y[u][j]); ++k; }
#pragma unroll
        for (int i = 0; i < MM; ++i)
#pragma unroll
            for (int j = 0; j < MM; ++j) { acc[k] += dot4(x[u][i], y[u][j]); ++k; }
    }

    // Wave (64-lane) butterfly reduce, then cross-wave via LDS.
#pragma unroll
    for (int k = 0; k < NACC; ++k) {
        float v = acc[k];
        for (int off = 32; off > 0; off >>= 1) v += __shfl_down(v, off, 64);
        acc[k] = v;
    }

    __shared__ float red[NTHREADS / 64][NACC];
    const int wave = threadIdx.x >> 6;
    const int lane = threadIdx.x & 63;
    if (lane == 0) {
#pragma unroll
        for (int k = 0; k < NACC; ++k) red[wave][k] = acc[k];
    }
    __syncthreads();
    if (threadIdx.x < NACC) {
        const int k = threadIdx.x;
        float s = red[0][k] + red[1][k] + red[2][k] + red[3][k];
        partial[(size_t)blockIdx.x * NACC + k] = s;
    }
}

__global__ __launch_bounds__(1024) void mmd_final_kernel(
    const float* __restrict__ partial, const float* __restrict__ wt,
    const float* __restrict__ wtout, float* __restrict__ out)
{
    __shared__ float acc_s[NB][NACC];
    // Parallel reduce over BPG blocks for each (b, k) pair.
    for (int p = threadIdx.x; p < NB * NACC; p += 1024) {
        const int b = p / NACC;
        const int k = p % NACC;
        float s = 0.0f;
        for (int blk = 0; blk < BPG; ++blk)
            s += partial[((size_t)b * BPG + blk) * NACC + k];
        acc_s[b][k] = s;
    }
    __syncthreads();

    __shared__ float lds[NB];
    const int b = threadIdx.x;
    if (b < NB) {
        const float* a = acc_s[b];
        float ss[MM][MM], rr[MM][MM], sg[MM][MM];
        {
            int k = 0;
            for (int i = 0; i < MM; ++i)
                for (int j = i; j < MM; ++j) { ss[i][j] = a[k]; ss[j][i] = a[k]; ++k; }
            for (int i = 0; i < MM; ++i)
                for (int j = i; j < MM; ++j) { rr[i][j] = a[k]; rr[j][i] = a[k]; ++k; }
            for (int i = 0; i < MM; ++i)
                for (int j = 0; j < MM; ++j) { sg[i][j] = a[k]; ++k; }
        }

        const float w    = wt[b];
        const float invD = 1.0f / (float)DD;  // sigma = 1
        auto kv = [&](float d2) -> float {
            d2 = fmaxf(d2, 1e-12f);
            float dist = sqrtf(d2) * invD;
            float e = -dist * w;
            e = fminf(fmaxf(e, -1e6f), 0.0f);
            return expf(e);
        };

        float mss = 0.0f, mrr = 0.0f, msr = 0.0f;
        for (int i = 0; i < MM; ++i) {
            for (int j = 0; j < MM; ++j) {
                mss += kv(ss[i][i] + ss[j][j] - 2.0f * ss[i][j]);
                mrr += kv(rr[i][i] + rr[j][j] - 2.0f * rr[i][j]);
                msr += kv(ss[i][i] + rr[j][j] - 2.0f * sg[i][j]);
            }
        }
        const float inv16 = 1.0f / 16.0f;
        float loss_raw = mss * inv16 + mrr * inv16 - 2.0f * (msr * inv16);
        lds[b] = wtout[b] * loss_raw;
    }
    __syncthreads();
    if (threadIdx.x == 0) {
        float s = 0.0f;
        for (int i = 0; i < NB; ++i) s += lds[i];
        out[0] = s / (float)NB;
    }
}

extern "C" void kernel_launch(void* const* d_in, const int* in_sizes, int n_in,
                              void* d_out, int out_size, void* d_ws, size_t ws_size,
                              hipStream_t stream) {
    const float* f_st  = (const float*)d_in[0];
    const float* f_sr  = (const float*)d_in[1];
    const float* wt    = (const float*)d_in[2];
    const float* wtout = (const float*)d_in[3];
    float* out     = (float*)d_out;
    float* partial = (float*)d_ws;   // NB*BPG*NACC floats = 294912 B

    mmd_partial_kernel<<<NB * BPG, NTHREADS, 0, stream>>>(f_st, f_sr, partial);
    mmd_final_kernel<<<1, 1024, 0, stream>>>(partial, wt, wtout, out);
}

// Round 3
// 44.419 us; speedup vs baseline: 2.6677x; 2.6677x over previous
//
#include <hip/hip_runtime.h>

// IMMLoss: B=32 groups, M=4 rows, D=196608 features, f32.
// loss = mean_b( wtout[b] * (mean K(st,st) + mean K(sr,sr) - 2*mean K(st,sr)) )
// K(x,y)_ij = exp(clip(-w[b]*sqrt(max(|x_i-y_j|^2,1e-12))/D, -1e6, 0))
// Streaming Gram accumulation, global_load_lds double-buffered.

constexpr int NB = 32;       // groups
constexpr int MM = 4;        // rows per group (8 combined rows: 4 st + 4 sr)
constexpr int DD = 196608;   // feature dim
constexpr int D4 = DD / 4;   // 49152 float4 per row
constexpr int BPG = 16;      // blocks per group -> 512 blocks = 2 per CU
constexpr int NTHREADS = 256;
constexpr int CHUNK4 = D4 / BPG;   // 3072 float4 columns per block
constexpr int TB = 256;            // columns per buffer iteration
constexpr int NITER = CHUNK4 / TB; // 12
constexpr int NACC = 36;           // 10 ss-tri + 10 rr-tri + 16 cross

__device__ __forceinline__ void gl_lds16(const float4* gsrc, float4* lds_dst) {
    __builtin_amdgcn_global_load_lds(
        (const __attribute__((address_space(1))) void*)gsrc,
        (__attribute__((address_space(3))) void*)lds_dst,
        16, 0, 0);
}

__device__ __forceinline__ float dot4(const float4& a, const float4& b) {
    return a.x * b.x + a.y * b.y + a.z * b.z + a.w * b.w;
}

__global__ __launch_bounds__(NTHREADS) void mmd_partial_kernel(
    const float* __restrict__ st, const float* __restrict__ sr,
    float* __restrict__ partial)
{
    __shared__ float4 buf[2][8][TB];   // 64 KiB double buffer

    const int b   = blockIdx.x / BPG;
    const int blk = blockIdx.x % BPG;
    const int c0  = blk * CHUNK4;

    const float4* stb = reinterpret_cast<const float4*>(st) + (size_t)b * MM * D4;
    const float4* srb = reinterpret_cast<const float4*>(sr) + (size_t)b * MM * D4;

    // Combined row pointers: rows 0-3 = st, rows 4-7 = sr.
    const float4* rowp[8];
#pragma unroll
    for (int r = 0; r < 4; ++r) rowp[r]     = stb + (size_t)r * D4 + c0;
#pragma unroll
    for (int r = 0; r < 4; ++r) rowp[4 + r] = srb + (size_t)r * D4 + c0;

    const int wave = threadIdx.x >> 6;   // 0..3: stages rows 2w, 2w+1
    const int lane = threadIdx.x & 63;

    // STAGE iteration `it` into buffer `cur`: 8 global_load_lds per wave,
    // each 64 lanes x 16B = 1KB. LDS dest is wave-uniform; lane offset is HW.
    auto stage = [&](int cur, int it) {
        const int cc = it * TB;
#pragma unroll
        for (int rr = 0; rr < 2; ++rr) {
            const int r = 2 * wave + rr;
            const float4* src = rowp[r] + cc + lane;
#pragma unroll
            for (int q = 0; q < 4; ++q) {
                gl_lds16(src + q * 64, &buf[cur][r][q * 64]);
            }
        }
    };

    float acc[NACC];
#pragma unroll
    for (int k = 0; k < NACC; ++k) acc[k] = 0.0f;

    stage(0, 0);   // prologue

    for (int it = 0; it < NITER; ++it) {
        const int cur = it & 1;
        // Barrier: implicit vmcnt(0) drain -> buf[cur] fully in LDS,
        // and all waves done reading buf[cur^1] from the previous iter.
        asm volatile("s_waitcnt vmcnt(0)");
        __syncthreads();
        if (it + 1 < NITER) stage(cur ^ 1, it + 1);   // async prefetch

        const int col = threadIdx.x;
        float4 x[8];
#pragma unroll
        for (int r = 0; r < 8; ++r) x[r] = buf[cur][r][col];

        int k = 0;
#pragma unroll
        for (int i = 0; i < MM; ++i)
#pragma unroll
            for (int j = i; j < MM; ++j) { acc[k] += dot4(x[i], x[j]); ++k; }
#pragma unroll
        for (int i = 0; i < MM; ++i)
#pragma unroll
            for (int j = i; j < MM; ++j) { acc[k] += dot4(x[4 + i], x[4 + j]); ++k; }
#pragma unroll
        for (int i = 0; i < MM; ++i)
#pragma unroll
            for (int j = 0; j < MM; ++j) { acc[k] += dot4(x[i], x[4 + j]); ++k; }
    }

    // Wave (64-lane) butterfly reduce, then cross-wave via LDS.
#pragma unroll
    for (int k = 0; k < NACC; ++k) {
        float v = acc[k];
        for (int off = 32; off > 0; off >>= 1) v += __shfl_down(v, off, 64);
        acc[k] = v;
    }

    __shared__ float red[NTHREADS / 64][NACC];
    if (lane == 0) {
#pragma unroll
        for (int k = 0; k < NACC; ++k) red[wave][k] = acc[k];
    }
    __syncthreads();
    if (threadIdx.x < NACC) {
        const int k = threadIdx.x;
        float s = red[0][k] + red[1][k] + red[2][k] + red[3][k];
        partial[(size_t)blockIdx.x * NACC + k] = s;
    }
}

__global__ __launch_bounds__(1024) void mmd_final_kernel(
    const float* __restrict__ partial, const float* __restrict__ wt,
    const float* __restrict__ wtout, float* __restrict__ out)
{
    __shared__ float acc_s[NB][NACC];
    for (int p = threadIdx.x; p < NB * NACC; p += 1024) {
        const int b = p / NACC;
        const int k = p % NACC;
        float s = 0.0f;
        for (int blk = 0; blk < BPG; ++blk)
            s += partial[((size_t)b * BPG + blk) * NACC + k];
        acc_s[b][k] = s;
    }
    __syncthreads();

    __shared__ float lds[NB];
    const int b = threadIdx.x;
    if (b < NB) {
        const float* a = acc_s[b];
        float ss[MM][MM], rr[MM][MM], sg[MM][MM];
        {
            int k = 0;
            for (int i = 0; i < MM; ++i)
                for (int j = i; j < MM; ++j) { ss[i][j] = a[k]; ss[j][i] = a[k]; ++k; }
            for (int i = 0; i < MM; ++i)
                for (int j = i; j < MM; ++j) { rr[i][j] = a[k]; rr[j][i] = a[k]; ++k; }
            for (int i = 0; i < MM; ++i)
                for (int j = 0; j < MM; ++j) { sg[i][j] = a[k]; ++k; }
        }

        const float w    = wt[b];
        const float invD = 1.0f / (float)DD;  // sigma = 1
        auto kv = [&](float d2) -> float {
            d2 = fmaxf(d2, 1e-12f);
            float dist = sqrtf(d2) * invD;
            float e = -dist * w;
            e = fminf(fmaxf(e, -1e6f), 0.0f);
            return expf(e);
        };

        float mss = 0.0f, mrr = 0.0f, msr = 0.0f;
        for (int i = 0; i < MM; ++i) {
            for (int j = 0; j < MM; ++j) {
                mss += kv(ss[i][i] + ss[j][j] - 2.0f * ss[i][j]);
                mrr += kv(rr[i][i] + rr[j][j] - 2.0f * rr[i][j]);
                msr += kv(ss[i][i] + rr[j][j] - 2.0f * sg[i][j]);
            }
        }
        const float inv16 = 1.0f / 16.0f;
        float loss_raw = mss * inv16 + mrr * inv16 - 2.0f * (msr * inv16);
        lds[b] = wtout[b] * loss_raw;
    }
    __syncthreads();
    if (threadIdx.x == 0) {
        float s = 0.0f;
        for (int i = 0; i < NB; ++i) s += lds[i];
        out[0] = s / (float)NB;
    }
}

extern "C" void kernel_launch(void* const* d_in, const int* in_sizes, int n_in,
                              void* d_out, int out_size, void* d_ws, size_t ws_size,
                              hipStream_t stream) {
    const float* f_st  = (const float*)d_in[0];
    const float* f_sr  = (const float*)d_in[1];
    const float* wt    = (const float*)d_in[2];
    const float* wtout = (const float*)d_in[3];
    float* out     = (float*)d_out;
    float* partial = (float*)d_ws;   // NB*BPG*NACC floats = 73728 B

    mmd_partial_kernel<<<NB * BPG, NTHREADS, 0, stream>>>(f_st, f_sr, partial);
    mmd_final_kernel<<<1, 1024, 0, stream>>>(partial, wt, wtout, out);
}